// Round 1
// baseline (392.652 us; speedup 1.0000x reference)
//
#include <hip/hip_runtime.h>

#define N_   64
#define C_   2048
#define HW_  288
#define P_   5
#define CM_  3328   // C_ + P_*256
#define LOC_ 1280   // P_*256

// ---------- DPP wave64 reductions (result valid in lane 63) ----------
template<int CTRL, int RMASK>
__device__ __forceinline__ float dpp_term(float x) {
  return __int_as_float(__builtin_amdgcn_update_dpp(0, __float_as_int(x), CTRL, RMASK, 0xF, true));
}
__device__ __forceinline__ float wave_sum63(float x) {
  x += dpp_term<0xB1, 0xF>(x);   // quad_perm xor1
  x += dpp_term<0x4E, 0xF>(x);   // quad_perm xor2
  x += dpp_term<0x141,0xF>(x);   // row_half_mirror
  x += dpp_term<0x140,0xF>(x);   // row_mirror
  x += dpp_term<0x142,0xA>(x);   // row_bcast15 -> rows 1,3
  x += dpp_term<0x143,0xC>(x);   // row_bcast31 -> rows 2,3
  return x;
}
__device__ __forceinline__ float wave_max63(float x) {
  x = fmaxf(x, dpp_term<0xB1, 0xF>(x));
  x = fmaxf(x, dpp_term<0x4E, 0xF>(x));
  x = fmaxf(x, dpp_term<0x141,0xF>(x));
  x = fmaxf(x, dpp_term<0x140,0xF>(x));
  x = fmaxf(x, dpp_term<0x142,0xA>(x));  // masked rows fmax with 0: unused by lane63 path
  x = fmaxf(x, dpp_term<0x143,0xC>(x));
  return x;
}

// ---------- Kernel A: boxes -> bitmasks + folded BN params ----------
__global__ __launch_bounds__(256) void kA(const float* __restrict__ poses,
    const float* __restrict__ lb, const float* __restrict__ lg, const float* __restrict__ lbe,
    const float* __restrict__ lm, const float* __restrict__ lv,
    const float* __restrict__ mb, const float* __restrict__ mg, const float* __restrict__ mbe,
    const float* __restrict__ mm, const float* __restrict__ mv,
    unsigned* __restrict__ mh, unsigned* __restrict__ mw, float* __restrict__ inva,
    float* __restrict__ locA, float* __restrict__ locB,
    float* __restrict__ mrgA, float* __restrict__ mrgB) {
  int t = blockIdx.x * 256 + threadIdx.x;
  if (t < 320) {
    int n = t / 5, p = t - 5 * (t / 5);
    const float* kp = poses + ((size_t)n * 17 + 4 * p) * 4;
    float px = kp[0], py = kp[1], z = kp[2];
    // exact reference op order, fp32 (np.round == rintf, half-to-even)
    float bx = fminf(fmaxf(px - 0.25f, 0.f), 0.75f) * z;
    float by = fminf(fmaxf(py - 0.25f, 0.f), 0.75f) * z;
    float bw = 0.5f * z;   // clip(0.5,0,0.75)=0.5
    float bh = 0.5f * z;
    int xs = (int)fmaxf(0.f,  rintf(12.f * bx));
    int xe = (int)fminf(11.f, rintf(12.f * (bx + bw)));
    int ys = (int)fmaxf(0.f,  rintf(24.f * by));
    int ye = (int)fminf(23.f, rintf(24.f * (by + bh)));
    mh[t] = ((1u << ye) - 1u) & ~((1u << ys) - 1u);
    mw[t] = ((1u << xe) - 1u) & ~((1u << xs) - 1u);
    int area = (ye - ys) * (xe - xs);
    inva[t] = area > 0 ? 1.f / (float)area : 1.f;
  } else if (t < 320 + LOC_) {
    int i = t - 320;
    float sc = lg[i] / sqrtf(lv[i] + 1e-5f);
    locA[i] = sc;
    locB[i] = (lb[i] - lm[i]) * sc + lbe[i];
  } else if (t < 320 + LOC_ + C_) {
    int j = t - 320 - LOC_;
    float sc = mg[j] / sqrtf(mv[j] + 1e-5f);
    mrgA[j] = sc;
    mrgB[j] = (mb[j] - mm[j]) * sc + mbe[j];
  }
}

// ---------- Kernel B: one wave per (n,c): box sums (avg) + global max (gfeat->cat) ----------
__global__ __launch_bounds__(256) void kB(const float* __restrict__ x,
    const unsigned* __restrict__ mhv, const unsigned* __restrict__ mwv,
    const float* __restrict__ inva,
    float* __restrict__ avg, float* __restrict__ cat) {
  int gw   = (blockIdx.x << 2) | (threadIdx.x >> 6);  // 0 .. N*C-1
  int lane = threadIdx.x & 63;
  int n = gw >> 11;
  int c = gw & 2047;
  const float4* xp = (const float4*)(x + (size_t)gw * HW_);
  unsigned MH[P_], MW[P_];
#pragma unroll
  for (int p = 0; p < P_; ++p) { MH[p] = mhv[n * P_ + p]; MW[p] = mwv[n * P_ + p]; }
  float s[P_] = {0.f, 0.f, 0.f, 0.f, 0.f};
  float4 v = xp[lane];                 // elements 4*lane .. 4*lane+3 (same image row)
  int e0 = lane << 2;
  int h  = e0 / 12;
  int w0 = e0 - h * 12;
  float mx = fmaxf(fmaxf(v.x, v.y), fmaxf(v.z, v.w));
#pragma unroll
  for (int p = 0; p < P_; ++p) {
    unsigned bits = (0u - ((MH[p] >> h) & 1u)) & (MW[p] >> w0);
    s[p] += (bits & 1u) ? v.x : 0.f;
    s[p] += (bits & 2u) ? v.y : 0.f;
    s[p] += (bits & 4u) ? v.z : 0.f;
    s[p] += (bits & 8u) ? v.w : 0.f;
  }
  if (lane < 8) {                      // tail elements 256..287
    float4 v2 = xp[64 + lane];
    int e1 = 256 + (lane << 2);
    int h1 = e1 / 12;
    int w1 = e1 - h1 * 12;
    mx = fmaxf(mx, fmaxf(fmaxf(v2.x, v2.y), fmaxf(v2.z, v2.w)));
#pragma unroll
    for (int p = 0; p < P_; ++p) {
      unsigned bits = (0u - ((MH[p] >> h1) & 1u)) & (MW[p] >> w1);
      s[p] += (bits & 1u) ? v2.x : 0.f;
      s[p] += (bits & 2u) ? v2.y : 0.f;
      s[p] += (bits & 4u) ? v2.z : 0.f;
      s[p] += (bits & 8u) ? v2.w : 0.f;
    }
  }
  mx = wave_max63(mx);
#pragma unroll
  for (int p = 0; p < P_; ++p) s[p] = wave_sum63(s[p]);
  if (lane == 63) {
    cat[(size_t)n * CM_ + LOC_ + c] = mx;
#pragma unroll
    for (int p = 0; p < P_; ++p)
      avg[((size_t)n * P_ + p) * C_ + c] = s[p] * inva[n * P_ + p];
  }
}

// ---------- shared 64x64 fp32 tile GEMM, C-split with atomic accumulate ----------
template<int GSEG>
__device__ __forceinline__ void gemm_tile(const float* __restrict__ Ag, int lda,
                                          const float* __restrict__ Wg, int ldw,
                                          float* __restrict__ Og, int ldo,
                                          float* As, float* Ws) {
  const int t  = threadIdx.x;
  const int nq = t & 15;          // output rows n = nq + 16*i
  const int kq = t >> 4;          // output cols k = kq + 16*j  (kq 0..15)
  const int c4 = (t & 15) << 2;
  const int rr = t >> 4;
  float acc[4][4] = {};
  for (int g = 0; g < GSEG; ++g) {
    __syncthreads();
#pragma unroll
    for (int i = 0; i < 4; ++i) {
      int r = rr + (i << 4);
      *(float4*)&As[r * 68 + c4] = *(const float4*)&Ag[(size_t)r * lda + (g << 6) + c4];
      *(float4*)&Ws[r * 68 + c4] = *(const float4*)&Wg[(size_t)r * ldw + (g << 6) + c4];
    }
    __syncthreads();
#pragma unroll
    for (int c = 0; c < 64; c += 4) {
      float4 a[4], w[4];
#pragma unroll
      for (int i = 0; i < 4; ++i) a[i] = *(const float4*)&As[(nq + (i << 4)) * 68 + c];
#pragma unroll
      for (int j = 0; j < 4; ++j) w[j] = *(const float4*)&Ws[(kq + (j << 4)) * 68 + c];
#pragma unroll
      for (int i = 0; i < 4; ++i)
#pragma unroll
        for (int j = 0; j < 4; ++j)
          acc[i][j] += a[i].x * w[j].x + a[i].y * w[j].y + a[i].z * w[j].z + a[i].w * w[j].w;
    }
  }
#pragma unroll
  for (int i = 0; i < 4; ++i)
#pragma unroll
    for (int j = 0; j < 4; ++j)
      atomicAdd(&Og[(size_t)(nq + (i << 4)) * ldo + kq + (j << 4)], acc[i][j]);
}

// loc GEMM: avg(64x2048, per-p) x local_w[p]^T -> cat[:, p*256+k]
__global__ __launch_bounds__(256) void kC(const float* __restrict__ avg,
                                          const float* __restrict__ local_w,
                                          float* __restrict__ cat) {
  __shared__ float As[64 * 68];
  __shared__ float Ws[64 * 68];
  int b  = blockIdx.x;            // 320 = 5p * 4kt * 16cg
  int p  = b >> 6;
  int kt = (b >> 4) & 3;
  int cg = b & 15;
  const float* Ag = avg + p * C_ + (cg << 7);
  const float* Wg = local_w + ((size_t)p * 256 + (kt << 6)) * C_ + (cg << 7);
  float* Og = cat + (p << 8) + (kt << 6);
  gemm_tile<2>(Ag, P_ * C_, Wg, C_, Og, CM_, As, Ws);
}

// BN+ReLU on loc region of cat
__global__ __launch_bounds__(256) void kC2(float* __restrict__ cat,
                                           const float* __restrict__ locA,
                                           const float* __restrict__ locB) {
  int i = blockIdx.x * 256 + threadIdx.x;   // < 64*1280
  int n = i / LOC_;
  int q = i - n * LOC_;
  size_t idx = (size_t)n * CM_ + q;
  float v = cat[idx] * locA[q] + locB[q];
  cat[idx] = fmaxf(v, 0.f);
}

// merge GEMM: cat(64x3328) x merge_w^T -> ybuf(64x2048)
__global__ __launch_bounds__(256) void kD(const float* __restrict__ cat,
                                          const float* __restrict__ merge_w,
                                          float* __restrict__ ybuf) {
  __shared__ float As[64 * 68];
  __shared__ float Ws[64 * 68];
  int b  = blockIdx.x;            // 832 = 32jt * 26cg
  int jt = b / 26;
  int cg = b - jt * 26;
  const float* Ag = cat + (cg << 7);
  const float* Wg = merge_w + (size_t)(jt << 6) * CM_ + (cg << 7);
  float* Og = ybuf + (jt << 6);
  gemm_tile<2>(Ag, CM_, Wg, CM_, Og, C_, As, Ws);
}

// BN+ReLU+L2 normalize -> d_out
__global__ __launch_bounds__(256) void kE(const float* __restrict__ ybuf,
                                          const float* __restrict__ mrgA,
                                          const float* __restrict__ mrgB,
                                          float* __restrict__ out) {
  int n = blockIdx.x, t = threadIdx.x;
  float z[8]; float ss = 0.f;
#pragma unroll
  for (int r = 0; r < 8; ++r) {
    int j = t + (r << 8);
    float v = ybuf[(size_t)n * C_ + j] * mrgA[j] + mrgB[j];
    v = fmaxf(v, 0.f);
    z[r] = v; ss += v * v;
  }
#pragma unroll
  for (int off = 32; off; off >>= 1) ss += __shfl_xor(ss, off, 64);
  __shared__ float red[4];
  if ((t & 63) == 0) red[t >> 6] = ss;
  __syncthreads();
  float tot = red[0] + red[1] + red[2] + red[3];
  float inv = 1.f / fmaxf(sqrtf(tot), 1e-12f);
#pragma unroll
  for (int r = 0; r < 8; ++r) out[(size_t)n * C_ + t + (r << 8)] = z[r] * inv;
}

extern "C" void kernel_launch(void* const* d_in, const int* in_sizes, int n_in,
                              void* d_out, int out_size, void* d_ws, size_t ws_size,
                              hipStream_t stream) {
  const float* x          = (const float*)d_in[0];
  const float* poses      = (const float*)d_in[1];
  const float* local_w    = (const float*)d_in[2];
  const float* local_b    = (const float*)d_in[3];
  const float* local_g    = (const float*)d_in[4];
  const float* local_be   = (const float*)d_in[5];
  const float* local_m    = (const float*)d_in[6];
  const float* local_v    = (const float*)d_in[7];
  const float* merge_w    = (const float*)d_in[8];
  const float* merge_b    = (const float*)d_in[9];
  const float* merge_g    = (const float*)d_in[10];
  const float* merge_be   = (const float*)d_in[11];
  const float* merge_m    = (const float*)d_in[12];
  const float* merge_v    = (const float*)d_in[13];

  float* ws   = (float*)d_ws;
  float* cat  = ws;                        // 64*3328   = 212992 floats
  float* ybuf = ws + 212992;               // 64*2048   = 131072
  float* avg  = ws + 344064;               // 64*5*2048 = 655360
  unsigned* mh = (unsigned*)(ws + 999424); // 320
  unsigned* mw = (unsigned*)(ws + 999744); // 320
  float* inva = ws + 1000064;              // 320
  float* locA = ws + 1000384;              // 1280
  float* locB = ws + 1001664;              // 1280
  float* mrgA = ws + 1002944;              // 2048
  float* mrgB = ws + 1004992;              // 2048

  // zero cat + ybuf (atomic accumulators; ws is poisoned before every launch)
  hipMemsetAsync(d_ws, 0, (size_t)344064 * sizeof(float), stream);

  kA<<<15, 256, 0, stream>>>(poses, local_b, local_g, local_be, local_m, local_v,
                             merge_b, merge_g, merge_be, merge_m, merge_v,
                             mh, mw, inva, locA, locB, mrgA, mrgB);
  kB<<<(N_ * C_) / 4, 256, 0, stream>>>(x, mh, mw, inva, avg, cat);
  kC<<<320, 256, 0, stream>>>(avg, local_w, cat);
  kC2<<<320, 256, 0, stream>>>(cat, locA, locB);
  kD<<<832, 256, 0, stream>>>(cat, merge_w, ybuf);
  kE<<<64, 256, 0, stream>>>(ybuf, mrgA, mrgB, (float*)d_out);
}

// Round 2
// 315.658 us; speedup vs baseline: 1.2439x; 1.2439x over previous
//
#include <hip/hip_runtime.h>

#define N_   64
#define C_   2048
#define HW_  288
#define P_   5
#define CM_  3328   // C_ + P_*256
#define LOC_ 1280   // P_*256
#define SEGC 8      // K segments for loc GEMM  (2048/256)
#define SEGM 13     // K segments for merge GEMM (3328/256)

// ---------- DPP wave64 reductions (result valid in lane 63) ----------
template<int CTRL, int RMASK>
__device__ __forceinline__ float dpp_term(float x) {
  return __int_as_float(__builtin_amdgcn_update_dpp(0, __float_as_int(x), CTRL, RMASK, 0xF, true));
}
__device__ __forceinline__ float wave_sum63(float x) {
  x += dpp_term<0xB1, 0xF>(x);   // quad_perm xor1
  x += dpp_term<0x4E, 0xF>(x);   // quad_perm xor2
  x += dpp_term<0x141,0xF>(x);   // row_half_mirror
  x += dpp_term<0x140,0xF>(x);   // row_mirror
  x += dpp_term<0x142,0xA>(x);   // row_bcast15 -> rows 1,3
  x += dpp_term<0x143,0xC>(x);   // row_bcast31 -> rows 2,3
  return x;
}
__device__ __forceinline__ float wave_max63(float x) {
  x = fmaxf(x, dpp_term<0xB1, 0xF>(x));
  x = fmaxf(x, dpp_term<0x4E, 0xF>(x));
  x = fmaxf(x, dpp_term<0x141,0xF>(x));
  x = fmaxf(x, dpp_term<0x140,0xF>(x));
  x = fmaxf(x, dpp_term<0x142,0xA>(x));
  x = fmaxf(x, dpp_term<0x143,0xC>(x));
  return x;
}

// ---------- Kernel A: boxes -> bitmasks + folded BN params ----------
__global__ __launch_bounds__(256) void kA(const float* __restrict__ poses,
    const float* __restrict__ lb, const float* __restrict__ lg, const float* __restrict__ lbe,
    const float* __restrict__ lm, const float* __restrict__ lv,
    const float* __restrict__ mb, const float* __restrict__ mg, const float* __restrict__ mbe,
    const float* __restrict__ mm, const float* __restrict__ mv,
    unsigned* __restrict__ mh, unsigned* __restrict__ mw, float* __restrict__ inva,
    float* __restrict__ locA, float* __restrict__ locB,
    float* __restrict__ mrgA, float* __restrict__ mrgB) {
  int t = blockIdx.x * 256 + threadIdx.x;
  if (t < 320) {
    int n = t / 5, p = t - 5 * (t / 5);
    const float* kp = poses + ((size_t)n * 17 + 4 * p) * 4;
    float px = kp[0], py = kp[1], z = kp[2];
    float bx = fminf(fmaxf(px - 0.25f, 0.f), 0.75f) * z;
    float by = fminf(fmaxf(py - 0.25f, 0.f), 0.75f) * z;
    float bw = 0.5f * z;
    float bh = 0.5f * z;
    int xs = (int)fmaxf(0.f,  rintf(12.f * bx));
    int xe = (int)fminf(11.f, rintf(12.f * (bx + bw)));
    int ys = (int)fmaxf(0.f,  rintf(24.f * by));
    int ye = (int)fminf(23.f, rintf(24.f * (by + bh)));
    mh[t] = ((1u << ye) - 1u) & ~((1u << ys) - 1u);
    mw[t] = ((1u << xe) - 1u) & ~((1u << xs) - 1u);
    int area = (ye - ys) * (xe - xs);
    inva[t] = area > 0 ? 1.f / (float)area : 1.f;
  } else if (t < 320 + LOC_) {
    int i = t - 320;
    float sc = lg[i] / sqrtf(lv[i] + 1e-5f);
    locA[i] = sc;
    locB[i] = (lb[i] - lm[i]) * sc + lbe[i];
  } else if (t < 320 + LOC_ + C_) {
    int j = t - 320 - LOC_;
    float sc = mg[j] / sqrtf(mv[j] + 1e-5f);
    mrgA[j] = sc;
    mrgB[j] = (mb[j] - mm[j]) * sc + mbe[j];
  }
}

// ---------- Kernel B: one wave per (n,c): box sums (avg) + global max (gfeat->cat) ----------
__global__ __launch_bounds__(256) void kB(const float* __restrict__ x,
    const unsigned* __restrict__ mhv, const unsigned* __restrict__ mwv,
    const float* __restrict__ inva,
    float* __restrict__ avg, float* __restrict__ cat) {
  int gw   = (blockIdx.x << 2) | (threadIdx.x >> 6);  // 0 .. N*C-1
  int lane = threadIdx.x & 63;
  int n = gw >> 11;
  int c = gw & 2047;
  const float4* xp = (const float4*)(x + (size_t)gw * HW_);
  unsigned MH[P_], MW[P_];
#pragma unroll
  for (int p = 0; p < P_; ++p) { MH[p] = mhv[n * P_ + p]; MW[p] = mwv[n * P_ + p]; }
  float s[P_] = {0.f, 0.f, 0.f, 0.f, 0.f};
  float4 v = xp[lane];
  int e0 = lane << 2;
  int h  = e0 / 12;
  int w0 = e0 - h * 12;
  float mx = fmaxf(fmaxf(v.x, v.y), fmaxf(v.z, v.w));
#pragma unroll
  for (int p = 0; p < P_; ++p) {
    unsigned bits = (0u - ((MH[p] >> h) & 1u)) & (MW[p] >> w0);
    s[p] += (bits & 1u) ? v.x : 0.f;
    s[p] += (bits & 2u) ? v.y : 0.f;
    s[p] += (bits & 4u) ? v.z : 0.f;
    s[p] += (bits & 8u) ? v.w : 0.f;
  }
  if (lane < 8) {
    float4 v2 = xp[64 + lane];
    int e1 = 256 + (lane << 2);
    int h1 = e1 / 12;
    int w1 = e1 - h1 * 12;
    mx = fmaxf(mx, fmaxf(fmaxf(v2.x, v2.y), fmaxf(v2.z, v2.w)));
#pragma unroll
    for (int p = 0; p < P_; ++p) {
      unsigned bits = (0u - ((MH[p] >> h1) & 1u)) & (MW[p] >> w1);
      s[p] += (bits & 1u) ? v2.x : 0.f;
      s[p] += (bits & 2u) ? v2.y : 0.f;
      s[p] += (bits & 4u) ? v2.z : 0.f;
      s[p] += (bits & 8u) ? v2.w : 0.f;
    }
  }
  mx = wave_max63(mx);
#pragma unroll
  for (int p = 0; p < P_; ++p) s[p] = wave_sum63(s[p]);
  if (lane == 63) {
    cat[(size_t)n * CM_ + LOC_ + c] = mx;
#pragma unroll
    for (int p = 0; p < P_; ++p)
      avg[((size_t)n * P_ + p) * C_ + c] = s[p] * inva[n * P_ + p];
  }
}

// ---------- shared 64x64 fp32 tile GEMM over GSEG 64-chunks of K; plain stores ----------
template<int GSEG>
__device__ __forceinline__ void gemm_tile(const float* __restrict__ Ag, int lda,
                                          const float* __restrict__ Wg, int ldw,
                                          float* __restrict__ Og, int ldo,
                                          float* As, float* Ws) {
  const int t  = threadIdx.x;
  const int nq = t & 15;          // output rows n = nq + 16*i
  const int kq = t >> 4;          // output cols k = kq + 16*j
  const int c4 = (t & 15) << 2;
  const int rr = t >> 4;
  float acc[4][4] = {};
  for (int g = 0; g < GSEG; ++g) {
    __syncthreads();
#pragma unroll
    for (int i = 0; i < 4; ++i) {
      int r = rr + (i << 4);
      *(float4*)&As[r * 68 + c4] = *(const float4*)&Ag[(size_t)r * lda + (g << 6) + c4];
      *(float4*)&Ws[r * 68 + c4] = *(const float4*)&Wg[(size_t)r * ldw + (g << 6) + c4];
    }
    __syncthreads();
#pragma unroll
    for (int c = 0; c < 64; c += 4) {
      float4 a[4], w[4];
#pragma unroll
      for (int i = 0; i < 4; ++i) a[i] = *(const float4*)&As[(nq + (i << 4)) * 68 + c];
#pragma unroll
      for (int j = 0; j < 4; ++j) w[j] = *(const float4*)&Ws[(kq + (j << 4)) * 68 + c];
#pragma unroll
      for (int i = 0; i < 4; ++i)
#pragma unroll
        for (int j = 0; j < 4; ++j)
          acc[i][j] += a[i].x * w[j].x + a[i].y * w[j].y + a[i].z * w[j].z + a[i].w * w[j].w;
    }
  }
#pragma unroll
  for (int i = 0; i < 4; ++i)
#pragma unroll
    for (int j = 0; j < 4; ++j)
      Og[(size_t)(nq + (i << 4)) * ldo + kq + (j << 4)] = acc[i][j];
}

// loc GEMM partials: avg(64x2048 per-p) x local_w[p]^T -> locP[seg][64][1280]
__global__ __launch_bounds__(256) void kC(const float* __restrict__ avg,
                                          const float* __restrict__ local_w,
                                          float* __restrict__ locP) {
  __shared__ float As[64 * 68];
  __shared__ float Ws[64 * 68];
  int b  = blockIdx.x;            // 160 = (5p * 4kt) tiles * 8 segs
  int tl = b >> 3;                // tile 0..19
  int sg = b & 7;                 // K segment (256 wide)
  int p  = tl >> 2;
  int kt = tl & 3;
  const float* Ag = avg + p * C_ + (sg << 8);
  const float* Wg = local_w + ((size_t)p * 256 + (kt << 6)) * C_ + (sg << 8);
  float* Og = locP + (size_t)sg * (N_ * LOC_) + (p << 8) + (kt << 6);
  gemm_tile<4>(Ag, P_ * C_, Wg, C_, Og, LOC_, As, Ws);
}

// reduce locP over segs + BN + ReLU -> cat[:, 0:1280]
__global__ __launch_bounds__(256) void kC2(const float* __restrict__ locP,
                                           const float* __restrict__ locA,
                                           const float* __restrict__ locB,
                                           float* __restrict__ cat) {
  int i = blockIdx.x * 256 + threadIdx.x;   // < 64*1280
  int n = i / LOC_;
  int q = i - n * LOC_;
  float s = 0.f;
#pragma unroll
  for (int sg = 0; sg < SEGC; ++sg) s += locP[(size_t)sg * (N_ * LOC_) + i];
  float v = s * locA[q] + locB[q];
  cat[(size_t)n * CM_ + q] = fmaxf(v, 0.f);
}

// merge GEMM partials: cat(64x3328) x merge_w^T -> mrgP[seg][64][2048]
__global__ __launch_bounds__(256) void kD(const float* __restrict__ cat,
                                          const float* __restrict__ merge_w,
                                          float* __restrict__ mrgP) {
  __shared__ float As[64 * 68];
  __shared__ float Ws[64 * 68];
  int b  = blockIdx.x;            // 416 = 32 jt * 13 segs
  int jt = b / SEGM;
  int sg = b - jt * SEGM;
  const float* Ag = cat + (sg << 8);
  const float* Wg = merge_w + (size_t)(jt << 6) * CM_ + (sg << 8);
  float* Og = mrgP + (size_t)sg * (N_ * C_) + (jt << 6);
  gemm_tile<4>(Ag, CM_, Wg, CM_, Og, C_, As, Ws);
}

// reduce mrgP over segs + BN + ReLU + L2 normalize -> d_out
__global__ __launch_bounds__(256) void kE(const float* __restrict__ mrgP,
                                          const float* __restrict__ mrgA,
                                          const float* __restrict__ mrgB,
                                          float* __restrict__ out) {
  int n = blockIdx.x, t = threadIdx.x;
  float z[8]; float ss = 0.f;
#pragma unroll
  for (int r = 0; r < 8; ++r) {
    int j = t + (r << 8);
    float y = 0.f;
#pragma unroll
    for (int sg = 0; sg < SEGM; ++sg) y += mrgP[(size_t)sg * (N_ * C_) + (size_t)n * C_ + j];
    float v = y * mrgA[j] + mrgB[j];
    v = fmaxf(v, 0.f);
    z[r] = v; ss += v * v;
  }
#pragma unroll
  for (int off = 32; off; off >>= 1) ss += __shfl_xor(ss, off, 64);
  __shared__ float red[4];
  if ((t & 63) == 0) red[t >> 6] = ss;
  __syncthreads();
  float tot = red[0] + red[1] + red[2] + red[3];
  float inv = 1.f / fmaxf(sqrtf(tot), 1e-12f);
#pragma unroll
  for (int r = 0; r < 8; ++r) out[(size_t)n * C_ + t + (r << 8)] = z[r] * inv;
}

extern "C" void kernel_launch(void* const* d_in, const int* in_sizes, int n_in,
                              void* d_out, int out_size, void* d_ws, size_t ws_size,
                              hipStream_t stream) {
  const float* x          = (const float*)d_in[0];
  const float* poses      = (const float*)d_in[1];
  const float* local_w    = (const float*)d_in[2];
  const float* local_b    = (const float*)d_in[3];
  const float* local_g    = (const float*)d_in[4];
  const float* local_be   = (const float*)d_in[5];
  const float* local_m    = (const float*)d_in[6];
  const float* local_v    = (const float*)d_in[7];
  const float* merge_w    = (const float*)d_in[8];
  const float* merge_b    = (const float*)d_in[9];
  const float* merge_g    = (const float*)d_in[10];
  const float* merge_be   = (const float*)d_in[11];
  const float* merge_m    = (const float*)d_in[12];
  const float* merge_v    = (const float*)d_in[13];

  float* ws   = (float*)d_ws;
  float* cat  = ws;                          // 64*3328           = 212992
  float* avg  = ws + 212992;                 // 64*5*2048         = 655360
  float* locP = ws + 868352;                 // 8 * 64*1280       = 655360
  float* mrgP = ws + 1523712;                // 13 * 64*2048      = 1703936
  float* prm  = ws + 3227648;
  unsigned* mh = (unsigned*)(prm);           // 320
  unsigned* mw = (unsigned*)(prm + 320);     // 320
  float* inva = prm + 640;                   // 320
  float* locA = prm + 960;                   // 1280
  float* locB = prm + 2240;                  // 1280
  float* mrgA = prm + 3520;                  // 2048
  float* mrgB = prm + 5568;                  // 2048

  kA<<<15, 256, 0, stream>>>(poses, local_b, local_g, local_be, local_m, local_v,
                             merge_b, merge_g, merge_be, merge_m, merge_v,
                             mh, mw, inva, locA, locB, mrgA, mrgB);
  kB<<<(N_ * C_) / 4, 256, 0, stream>>>(x, mh, mw, inva, avg, cat);
  kC<<<20 * SEGC, 256, 0, stream>>>(avg, local_w, locP);
  kC2<<<(N_ * LOC_) / 256, 256, 0, stream>>>(locP, locA, locB, cat);
  kD<<<32 * SEGM, 256, 0, stream>>>(cat, merge_w, mrgP);
  kE<<<N_, 256, 0, stream>>>(mrgP, mrgA, mrgB, (float*)d_out);
}